// Round 4
// baseline (1203.580 us; speedup 1.0000x reference)
//
#include <hip/hip_runtime.h>
#include <math.h>

// ---- problem constants ----
static constexpr int N_   = 10000;
static constexpr int E_   = 160000;
static constexpr int G_   = 64;
static constexpr int T_   = 5;
static constexpr int FIN_ = 75;
static constexpr int ED_  = 50;
static constexpr int FOUT_= 15;
static constexpr int TF_  = T_*FIN_;     // 375
static constexpr int AGGW_= 4*FIN_;      // 300
static constexpr int YC_  = 48;          // padded 45 -> 48 combined outputs
static constexpr int H80  = 80;
static constexpr int ABW_ = 800;         // AB row: 10 chunks x 80
static constexpr int NP_  = 10048;       // padded node count (column-major feature rows)

// ---- UAF ----
__device__ __forceinline__ float softplus_f(float x){
    return fmaxf(x, 0.f) + log1pf(expf(-fabsf(x)));
}
__device__ __forceinline__ float uaf_f(float v, const float* __restrict__ p){
    return softplus_f(p[0]*(v + p[1]) + p[2]*v*v) - softplus_f(p[3]*(v - p[1])) + p[4];
}

// ---- setup kernels ----
__global__ void k_h0(const int* __restrict__ x, const float* __restrict__ node_emb, float* __restrict__ hT){
    int i = blockIdx.x*blockDim.x + threadIdx.x;
    if (i >= FIN_*N_) return;
    int q = i / N_, n = i % N_;
    hT[(size_t)q*NP_ + n] = node_emb[x[n]*FIN_ + q];
}

__global__ void k_deg(const int* __restrict__ ei, int* __restrict__ deg_i){
    int e = blockIdx.x*blockDim.x + threadIdx.x;
    if (e >= E_) return;
    atomicAdd(&deg_i[ei[E_ + e]], 1);
}

__global__ void k_scan(const int* __restrict__ deg_i, int* __restrict__ offs, float* __restrict__ avglog){
    __shared__ int sd[1024];
    __shared__ float sf[1024];
    __shared__ int carry;
    if (threadIdx.x == 0) carry = 0;
    __syncthreads();
    float ls = 0.f;
    for (int base = 0; base < N_; base += 1024){
        int i = base + threadIdx.x;
        int v = (i < N_) ? deg_i[i] : 0;
        if (i < N_) ls += logf((float)v + 1.f);
        sd[threadIdx.x] = v;
        __syncthreads();
        for (int off = 1; off < 1024; off <<= 1){
            int t = (threadIdx.x >= off) ? sd[threadIdx.x - off] : 0;
            __syncthreads();
            sd[threadIdx.x] += t;
            __syncthreads();
        }
        if (i < N_) offs[i] = carry + sd[threadIdx.x] - v;
        __syncthreads();
        if (threadIdx.x == 0) carry += sd[1023];
        __syncthreads();
    }
    if (threadIdx.x == 0) offs[N_] = carry;
    sf[threadIdx.x] = ls;
    __syncthreads();
    for (int off = 512; off > 0; off >>= 1){
        if (threadIdx.x < off) sf[threadIdx.x] += sf[threadIdx.x + off];
        __syncthreads();
    }
    if (threadIdx.x == 0) avglog[0] = sf[0] / (float)N_;
}

__global__ void k_fill(const int* __restrict__ ei, const int* __restrict__ eattr,
                       const int* __restrict__ offs, int* __restrict__ cursor, int* __restrict__ csr){
    int e = blockIdx.x*blockDim.x + threadIdx.x;
    if (e >= E_) return;
    int d = ei[E_ + e];
    int pos = offs[d] + atomicAdd(&cursor[d], 1);
    csr[pos] = ei[e] | (eattr[e] << 16);
}

__global__ void k_amp(const int* __restrict__ deg_i, const float* __restrict__ avglog,
                      float* __restrict__ ampv, float* __restrict__ iampv){
    int n = blockIdx.x*blockDim.x + threadIdx.x;
    if (n >= N_) return;
    float dm = fmaxf((float)deg_i[n], 1.f);
    float a = logf(dm + 1.f) / avglog[0];
    ampv[n] = a;
    iampv[n] = 1.f / a;
}

__global__ void k_eemb(const float* __restrict__ edge_emb, const float* __restrict__ We,
                       const float* __restrict__ be, float* __restrict__ eembw){
    int i = blockIdx.x*blockDim.x + threadIdx.x;
    if (i >= 4*4*FIN_) return;
    int c = i % FIN_;
    int a = (i / FIN_) % 4;
    int l = i / (4*FIN_);
    float s = be[l*FIN_ + c];
    for (int k = 0; k < ED_; k++) s = fmaf(edge_emb[a*ED_ + k], We[(l*ED_ + k)*FIN_ + c], s);
    eembw[i] = s;
}

__global__ void k_tbl(const float* __restrict__ eembw, const float* __restrict__ Wpre,
                      const float* __restrict__ bpre, float* __restrict__ tbl){
    int i = blockIdx.x*blockDim.x + threadIdx.x;
    if (i >= 4*4*TF_) return;
    int f = i % FIN_;
    int t = (i / FIN_) % T_;
    int a = (i / TF_) % 4;
    int l = i / (4*TF_);
    float s = bpre[(l*T_ + t)*FIN_ + f];
    const float* em = eembw + (l*4 + a)*FIN_;
    const float* W3 = Wpre + ((size_t)(l*T_ + t)*225 + 2*FIN_)*FIN_;
    for (int c = 0; c < FIN_; c++) s = fmaf(em[c], W3[c*FIN_ + f], s);
    tbl[i] = s;
}

// Wcomb[l,t,c,j]: 375x48 per (l,t). c: 0..74 h, 75..374 agg (kind-major). j: 0..14 y1, 15..29 y2(amp), 30..44 y3(iamp)
__global__ void k_wcomb(const float* __restrict__ Wpost, float* __restrict__ Wcomb){
    int i = blockIdx.x*blockDim.x + threadIdx.x;
    if (i >= 4*T_*TF_*YC_) return;
    int j = i % YC_;
    int c = (i / YC_) % TF_;
    int t = (i / (YC_*TF_)) % T_;
    int l = i / (YC_*TF_*T_);
    float v = 0.f;
    if (j < 45){
        int blk = j / 15, fo = j % 15;
        const float* Wp = Wpost + (size_t)(l*T_ + t)*975*15;
        if (c < FIN_){ if (blk == 0) v = Wp[c*15 + fo]; }
        else { int jj = c - FIN_; v = Wp[(FIN_ + blk*AGGW_ + jj)*15 + fo]; }
    }
    Wcomb[i] = v;
}

// ---- per-layer kernels ----
// thread-per-row GEMM, weights via wave-uniform (scalar) loads from global.
// AB[n, chunk*80 + j] = h_row @ W_block(75x75), chunk = t*2+half
__global__ void __launch_bounds__(64) k_A(const float* __restrict__ hT, const float* __restrict__ Wpre_l,
                                          float* __restrict__ AB){
    int chunk = blockIdx.y;
    int t = chunk >> 1, half = chunk & 1;
    const float* __restrict__ W = Wpre_l + (size_t)(t*225 + half*FIN_)*FIN_;
    int n = blockIdx.x*64 + threadIdx.x;
    int nn = (n < N_) ? n : N_-1;
    float acc[76];
    #pragma unroll
    for (int j = 0; j < 76; j++) acc[j] = 0.f;
    #pragma unroll 1
    for (int c4 = 0; c4 < 18; c4++){
        float i0 = hT[(size_t)(c4*4+0)*NP_ + nn];
        float i1 = hT[(size_t)(c4*4+1)*NP_ + nn];
        float i2 = hT[(size_t)(c4*4+2)*NP_ + nn];
        float i3 = hT[(size_t)(c4*4+3)*NP_ + nn];
        const float* W0 = W + c4*4*FIN_;
        #pragma unroll
        for (int j = 0; j < FIN_; j++){
            acc[j] = fmaf(i0, W0[j], acc[j]);
            acc[j] = fmaf(i1, W0[FIN_ + j], acc[j]);
            acc[j] = fmaf(i2, W0[2*FIN_ + j], acc[j]);
            acc[j] = fmaf(i3, W0[3*FIN_ + j], acc[j]);
        }
    }
    {   // tail c = 72..74
        float i0 = hT[(size_t)72*NP_ + nn];
        float i1 = hT[(size_t)73*NP_ + nn];
        float i2 = hT[(size_t)74*NP_ + nn];
        const float* W0 = W + 72*FIN_;
        #pragma unroll
        for (int j = 0; j < FIN_; j++){
            acc[j] = fmaf(i0, W0[j], acc[j]);
            acc[j] = fmaf(i1, W0[FIN_ + j], acc[j]);
            acc[j] = fmaf(i2, W0[2*FIN_ + j], acc[j]);
        }
    }
    if (n < N_){
        acc[75] = 0.f;
        float4* o = (float4*)(AB + (size_t)n*ABW_ + chunk*H80);
        #pragma unroll
        for (int j4 = 0; j4 < 19; j4++)
            o[j4] = make_float4(acc[4*j4], acc[4*j4+1], acc[4*j4+2], acc[4*j4+3]);
    }
}

// per-node CSR aggregation -> packed float4 {mean,mn,mx,sd} at agg2[(t*75+fi)*NP_ + n]
__global__ void __launch_bounds__(128) k_agg(const float* __restrict__ AB, const int* __restrict__ offs,
                                             const int* __restrict__ csr, const float* __restrict__ tbl_l,
                                             float4* __restrict__ agg2){
    __shared__ float tl[4*TF_];
    int bid = blockIdx.x;
    int n = (bid & 7)*1250 + (bid >> 3);   // XCD swizzle: line-sharing nodes on one XCD
    for (int idx = threadIdx.x; idx < 4*TF_; idx += 128) tl[idx] = tbl_l[idx];
    __syncthreads();
    int s = offs[n], e_end = offs[n+1];
    int f0 = threadIdx.x;
    int f1 = threadIdx.x + 128;
    int f2r = threadIdx.x + 256;
    int f2 = (f2r < TF_) ? f2r : 0;
    int ao0 = (f0/FIN_)*160 + f0%FIN_;
    int ao1 = (f1/FIN_)*160 + f1%FIN_;
    int ao2 = (f2/FIN_)*160 + f2%FIN_;
    const float* An = AB + (size_t)n*ABW_;
    float a0 = An[ao0], a1 = An[ao1], a2 = An[ao2];
    float s0=0.f,s1=0.f,s2=0.f, q0=0.f,q1=0.f,q2=0.f;
    float mn0=INFINITY,mn1=INFINITY,mn2=INFINITY;
    float mx0=-INFINITY,mx1=-INFINITY,mx2=-INFINITY;
    for (int e = s; e < e_end; e++){
        int pk = csr[e];
        int src = pk & 0xFFFF;
        int at = pk >> 16;
        const float* B = AB + (size_t)src*ABW_ + 80;
        const float* tt = tl + at*TF_;
        float m0 = a0 + B[ao0] + tt[f0];
        float m1 = a1 + B[ao1] + tt[f1];
        float m2 = a2 + B[ao2] + tt[f2];
        s0 += m0; s1 += m1; s2 += m2;
        q0 = fmaf(m0,m0,q0); q1 = fmaf(m1,m1,q1); q2 = fmaf(m2,m2,q2);
        mn0 = fminf(mn0,m0); mn1 = fminf(mn1,m1); mn2 = fminf(mn2,m2);
        mx0 = fmaxf(mx0,m0); mx1 = fmaxf(mx1,m1); mx2 = fmaxf(mx2,m2);
    }
    float deg = (float)(e_end - s);
    float dc = fmaxf(deg, 1.f);
    float inv = 1.f / dc;
    bool empty = (deg == 0.f);
    {
        float mean = s0*inv;
        float sd = sqrtf(fmaxf(q0*inv - mean*mean, 0.f) + 1e-5f);
        int t = f0/FIN_, fi = f0%FIN_;
        agg2[(size_t)(t*FIN_+fi)*NP_ + n] = make_float4(mean, empty?0.f:mn0, empty?0.f:mx0, sd);
    }
    {
        float mean = s1*inv;
        float sd = sqrtf(fmaxf(q1*inv - mean*mean, 0.f) + 1e-5f);
        int t = f1/FIN_, fi = f1%FIN_;
        agg2[(size_t)(t*FIN_+fi)*NP_ + n] = make_float4(mean, empty?0.f:mn1, empty?0.f:mx1, sd);
    }
    if (f2r < TF_){
        float mean = s2*inv;
        float sd = sqrtf(fmaxf(q2*inv - mean*mean, 0.f) + 1e-5f);
        int t = f2r/FIN_, fi = f2r%FIN_;
        agg2[(size_t)(t*FIN_+fi)*NP_ + n] = make_float4(mean, empty?0.f:mn2, empty?0.f:mx2, sd);
    }
}

// thread-per-row: YbT[(t*48 + jh*24 + j)*NP_ + n] = [h(75)|agg_t(300)] @ Wcomb[l,t][:, jh*24+j]
__global__ void __launch_bounds__(64) k_post3(const float* __restrict__ hT, const float4* __restrict__ agg2,
                                              const float* __restrict__ Wcomb_l, float* __restrict__ YbT){
    int t = blockIdx.y, jh = blockIdx.z;
    const float* __restrict__ W = Wcomb_l + (size_t)t*TF_*YC_ + jh*24;
    int n = blockIdx.x*64 + threadIdx.x;
    int nn = (n < N_) ? n : N_-1;
    float acc[24];
    #pragma unroll
    for (int j = 0; j < 24; j++) acc[j] = 0.f;
    // h part: W rows 0..74
    #pragma unroll 1
    for (int c4 = 0; c4 < 18; c4++){
        float i0 = hT[(size_t)(c4*4+0)*NP_ + nn];
        float i1 = hT[(size_t)(c4*4+1)*NP_ + nn];
        float i2 = hT[(size_t)(c4*4+2)*NP_ + nn];
        float i3 = hT[(size_t)(c4*4+3)*NP_ + nn];
        const float* W0 = W + c4*4*YC_;
        #pragma unroll
        for (int j = 0; j < 24; j++){
            acc[j] = fmaf(i0, W0[j], acc[j]);
            acc[j] = fmaf(i1, W0[YC_ + j], acc[j]);
            acc[j] = fmaf(i2, W0[2*YC_ + j], acc[j]);
            acc[j] = fmaf(i3, W0[3*YC_ + j], acc[j]);
        }
    }
    {
        float i0 = hT[(size_t)72*NP_ + nn];
        float i1 = hT[(size_t)73*NP_ + nn];
        float i2 = hT[(size_t)74*NP_ + nn];
        const float* W0 = W + 72*YC_;
        #pragma unroll
        for (int j = 0; j < 24; j++){
            acc[j] = fmaf(i0, W0[j], acc[j]);
            acc[j] = fmaf(i1, W0[YC_ + j], acc[j]);
            acc[j] = fmaf(i2, W0[2*YC_ + j], acc[j]);
        }
    }
    // agg part: per fi one coalesced b128 {mean,mn,mx,sd}; W rows 75 + kind*75 + fi
    const float4* ap = agg2 + (size_t)t*FIN_*NP_ + nn;
    #pragma unroll 1
    for (int fi = 0; fi < FIN_; fi++){
        float4 m = ap[(size_t)fi*NP_];
        const float* Wm = W + (FIN_ + fi)*YC_;
        #pragma unroll
        for (int j = 0; j < 24; j++){
            acc[j] = fmaf(m.x, Wm[j], acc[j]);
            acc[j] = fmaf(m.y, Wm[FIN_*YC_ + j], acc[j]);
            acc[j] = fmaf(m.z, Wm[2*FIN_*YC_ + j], acc[j]);
            acc[j] = fmaf(m.w, Wm[3*FIN_*YC_ + j], acc[j]);
        }
    }
    if (n < N_){
        #pragma unroll
        for (int j = 0; j < 24; j++) YbT[(size_t)(t*YC_ + jh*24 + j)*NP_ + n] = acc[j];
    }
}

// combine + Wlin + BN stats; thread-per-row
__global__ void __launch_bounds__(64) k_Y(const float* __restrict__ YbT, const float* __restrict__ ampv,
                                          const float* __restrict__ iampv, const float* __restrict__ bpost_l,
                                          const float* __restrict__ Wlin_l, const float* __restrict__ blin_l,
                                          float* __restrict__ olinT, float* __restrict__ bnsum, float* __restrict__ bnsq){
    __shared__ float st[64*77];
    int n = blockIdx.x*64 + threadIdx.x;
    int nn = (n < N_) ? n : N_-1;
    bool valid = (n < N_);
    float amp = ampv[nn], iamp = iampv[nn];
    #pragma unroll 1
    for (int t = 0; t < T_; t++){
        #pragma unroll
        for (int fo = 0; fo < FOUT_; fo++){
            float v = YbT[(size_t)(t*YC_ + fo)*NP_ + nn]
                    + amp  * YbT[(size_t)(t*YC_ + 15 + fo)*NP_ + nn]
                    + iamp * YbT[(size_t)(t*YC_ + 30 + fo)*NP_ + nn]
                    + bpost_l[t*FOUT_ + fo];
            st[threadIdx.x*77 + t*FOUT_ + fo] = v;
        }
    }
    float acc[FIN_];
    #pragma unroll
    for (int q = 0; q < FIN_; q++) acc[q] = blin_l[q];
    #pragma unroll 1
    for (int p = 0; p < FIN_; p++){
        float yv = st[threadIdx.x*77 + p];
        const float* Wp = Wlin_l + p*FIN_;
        #pragma unroll
        for (int q = 0; q < FIN_; q++) acc[q] = fmaf(yv, Wp[q], acc[q]);
    }
    if (valid){
        #pragma unroll
        for (int q = 0; q < FIN_; q++) olinT[(size_t)q*NP_ + n] = acc[q];
    }
    __syncthreads();
    #pragma unroll
    for (int q = 0; q < FIN_; q++) st[threadIdx.x*77 + q] = valid ? acc[q] : 0.f;
    __syncthreads();
    // BUGFIX R3->R4: 64 threads must cover 75 columns (was `if (tid < FIN_)`,
    // leaving cols 64..74 with zero stats -> rsqrt(eps) blowup over 4 layers).
    for (int q = threadIdx.x; q < FIN_; q += 64){
        float s = 0.f, s2 = 0.f;
        #pragma unroll 4
        for (int m = 0; m < 64; m++){ float v = st[m*77 + q]; s += v; s2 = fmaf(v, v, s2); }
        atomicAdd(&bnsum[q], s);
        atomicAdd(&bnsq[q], s2);
    }
}

__global__ void k_bn(const float* __restrict__ olinT, const float* __restrict__ bnsum, const float* __restrict__ bnsq,
                     const float* __restrict__ gamma_l, const float* __restrict__ beta_l,
                     const float* __restrict__ uafp, float* __restrict__ hT){
    int i = blockIdx.x*blockDim.x + threadIdx.x;
    if (i >= FIN_*N_) return;
    int q = i / N_, n = i % N_;
    float mu = bnsum[q] * (1.f/(float)N_);
    float var = bnsq[q] * (1.f/(float)N_) - mu*mu;
    float xh = (olinT[(size_t)q*NP_ + n] - mu) * rsqrtf(var + 1e-5f) * gamma_l[q] + beta_l[q];
    hT[(size_t)q*NP_ + n] = uaf_f(xh, uafp);
}

// ---- pooling + MLP ----
__global__ void k_pool(const float* __restrict__ hT, const int* __restrict__ batch, float* __restrict__ pooled){
    int i = blockIdx.x*blockDim.x + threadIdx.x;
    if (i >= FIN_*N_) return;
    int q = i / N_, n = i % N_;
    atomicAdd(&pooled[batch[n]*FIN_ + q], hT[(size_t)q*NP_ + n]);
}

__global__ void __launch_bounds__(64) k_mlp(const float* __restrict__ pooled,
        const float* __restrict__ mW1, const float* __restrict__ mb1,
        const float* __restrict__ mW2, const float* __restrict__ mb2,
        const float* __restrict__ mW3, const float* __restrict__ mb3,
        const float* __restrict__ uafp, float* __restrict__ outp){
    __shared__ float pr[FIN_];
    __shared__ float z1[50];
    __shared__ float z2[25];
    int g = blockIdx.x;
    for (int c = threadIdx.x; c < FIN_; c += 64) pr[c] = pooled[g*FIN_ + c];
    __syncthreads();
    if (threadIdx.x < 50){
        float s = mb1[threadIdx.x];
        for (int c = 0; c < FIN_; c++) s = fmaf(pr[c], mW1[c*50 + threadIdx.x], s);
        z1[threadIdx.x] = uaf_f(s, uafp);
    }
    __syncthreads();
    if (threadIdx.x < 25){
        float s = mb2[threadIdx.x];
        for (int c = 0; c < 50; c++) s = fmaf(z1[c], mW2[c*25 + threadIdx.x], s);
        z2[threadIdx.x] = uaf_f(s, uafp);
    }
    __syncthreads();
    if (threadIdx.x == 0){
        float s = mb3[0];
        for (int c = 0; c < 25; c++) s = fmaf(z2[c], mW3[c], s);
        outp[g] = s;
    }
}

extern "C" void kernel_launch(void* const* d_in, const int* in_sizes, int n_in,
                              void* d_out, int out_size, void* d_ws, size_t ws_size,
                              hipStream_t stream) {
    const int* x         = (const int*)d_in[0];
    const int* ei        = (const int*)d_in[1];
    const int* eattr     = (const int*)d_in[2];
    const int* batch     = (const int*)d_in[3];
    const float* node_emb= (const float*)d_in[4];
    const float* edge_emb= (const float*)d_in[5];
    const float* We      = (const float*)d_in[6];
    const float* be      = (const float*)d_in[7];
    const float* Wpre    = (const float*)d_in[8];
    const float* bpre    = (const float*)d_in[9];
    const float* Wpost   = (const float*)d_in[10];
    const float* bpost   = (const float*)d_in[11];
    const float* Wlin    = (const float*)d_in[12];
    const float* blin    = (const float*)d_in[13];
    const float* bn_gamma= (const float*)d_in[14];
    const float* bn_beta = (const float*)d_in[15];
    const float* uafp    = (const float*)d_in[16];
    const float* mW1     = (const float*)d_in[17];
    const float* mb1     = (const float*)d_in[18];
    const float* mW2     = (const float*)d_in[19];
    const float* mb2     = (const float*)d_in[20];
    const float* mW3     = (const float*)d_in[21];
    const float* mb3     = (const float*)d_in[22];
    float* outp          = (float*)d_out;

    char* w = (char*)d_ws;
    auto alloc = [&](size_t bytes) -> void* {
        void* p = (void*)w;
        w += (bytes + 255) & ~(size_t)255;
        return p;
    };
    float*  hT    = (float*)alloc((size_t)FIN_*NP_*4);
    float*  AB    = (float*)alloc((size_t)N_*ABW_*4);          // 32 MB
    float4* agg2  = (float4*)alloc((size_t)TF_*NP_*16);        // 60.3 MB
    float*  YbT   = AB;                  // alias: AB dead after k_agg (9.65 MB)
    float*  olinT = AB + 4000000;        // alias at +16 MB (3 MB), disjoint from YbT
    float*  ampv  = (float*)alloc(N_*4);
    float*  iampv = (float*)alloc(N_*4);
    float*  avglog= (float*)alloc(4);
    float*  tbl   = (float*)alloc(4*4*TF_*4);
    float*  eembw = (float*)alloc(4*4*FIN_*4);
    float*  Wcomb = (float*)alloc((size_t)4*T_*TF_*YC_*4);
    float*  bnsum = (float*)alloc(2*FIN_*4);
    float*  bnsq  = bnsum + FIN_;
    float*  pooled= (float*)alloc(G_*FIN_*4);
    int* deg_i   = (int*)alloc(N_*4);
    int* offs    = (int*)alloc((N_+1)*4);
    int* cursor  = (int*)alloc(N_*4);
    int* csr     = (int*)alloc(E_*4);

    hipMemsetAsync(deg_i, 0, N_*4, stream);
    hipMemsetAsync(cursor, 0, N_*4, stream);
    hipMemsetAsync(pooled, 0, G_*FIN_*4, stream);

    k_h0<<<(FIN_*N_ + 255)/256, 256, 0, stream>>>(x, node_emb, hT);
    k_deg<<<(E_ + 255)/256, 256, 0, stream>>>(ei, deg_i);
    k_scan<<<1, 1024, 0, stream>>>(deg_i, offs, avglog);
    k_fill<<<(E_ + 255)/256, 256, 0, stream>>>(ei, eattr, offs, cursor, csr);
    k_amp<<<(N_ + 255)/256, 256, 0, stream>>>(deg_i, avglog, ampv, iampv);
    k_eemb<<<(4*4*FIN_ + 255)/256, 256, 0, stream>>>(edge_emb, We, be, eembw);
    k_tbl<<<(4*4*TF_ + 255)/256, 256, 0, stream>>>(eembw, Wpre, bpre, tbl);
    k_wcomb<<<(4*T_*TF_*YC_ + 255)/256, 256, 0, stream>>>(Wpost, Wcomb);

    int nrb = (N_ + 63)/64;  // 157
    for (int l = 0; l < 4; l++){
        hipMemsetAsync(bnsum, 0, 2*FIN_*4, stream);
        k_A<<<dim3(nrb, 10), 64, 0, stream>>>(hT, Wpre + (size_t)l*T_*225*FIN_, AB);
        k_agg<<<N_, 128, 0, stream>>>(AB, offs, csr, tbl + (size_t)l*4*TF_, agg2);
        k_post3<<<dim3(nrb, T_, 2), 64, 0, stream>>>(hT, agg2, Wcomb + (size_t)l*T_*TF_*YC_, YbT);
        k_Y<<<nrb, 64, 0, stream>>>(YbT, ampv, iampv, bpost + l*T_*FOUT_,
                                    Wlin + (size_t)l*FIN_*FIN_, blin + l*FIN_,
                                    olinT, bnsum, bnsq);
        k_bn<<<(FIN_*N_ + 255)/256, 256, 0, stream>>>(olinT, bnsum, bnsq,
                                                      bn_gamma + l*FIN_, bn_beta + l*FIN_, uafp, hT);
    }

    k_pool<<<(FIN_*N_ + 255)/256, 256, 0, stream>>>(hT, batch, pooled);
    k_mlp<<<G_, 64, 0, stream>>>(pooled, mW1, mb1, mW2, mb2, mW3, mb3, uafp, outp);
}

// Round 6
// 1199.929 us; speedup vs baseline: 1.0030x; 1.0030x over previous
//
#include <hip/hip_runtime.h>
#include <hip/hip_fp16.h>
#include <math.h>

// ---- problem constants ----
static constexpr int N_   = 10000;
static constexpr int E_   = 160000;
static constexpr int G_   = 64;
static constexpr int T_   = 5;
static constexpr int FIN_ = 75;
static constexpr int ED_  = 50;
static constexpr int FOUT_= 15;
static constexpr int TF_  = T_*FIN_;     // 375
static constexpr int AGGW_= 4*FIN_;      // 300
static constexpr int YC_  = 48;          // padded 45 -> 48 combined outputs
static constexpr int NP_  = 10048;       // padded node count (column-major feature rows)
static constexpr int AW_  = 400;         // Af/Bh row: 5 chunks x 80

// ---- UAF ----
__device__ __forceinline__ float softplus_f(float x){
    return fmaxf(x, 0.f) + log1pf(expf(-fabsf(x)));
}
__device__ __forceinline__ float uaf_f(float v, const float* __restrict__ p){
    return softplus_f(p[0]*(v + p[1]) + p[2]*v*v) - softplus_f(p[3]*(v - p[1])) + p[4];
}
__device__ __forceinline__ unsigned pack2h(float a, float b){
    __half2 h = __floats2half2_rn(a, b);
    return *reinterpret_cast<unsigned*>(&h);
}

// ---- setup kernels ----
__global__ void k_h0(const int* __restrict__ x, const float* __restrict__ node_emb, float* __restrict__ hT){
    int i = blockIdx.x*blockDim.x + threadIdx.x;
    if (i >= FIN_*N_) return;
    int q = i / N_, n = i % N_;
    hT[(size_t)q*NP_ + n] = node_emb[x[n]*FIN_ + q];
}

__global__ void k_deg(const int* __restrict__ ei, int* __restrict__ deg_i){
    int e = blockIdx.x*blockDim.x + threadIdx.x;
    if (e >= E_) return;
    atomicAdd(&deg_i[ei[E_ + e]], 1);
}

__global__ void k_scan(const int* __restrict__ deg_i, int* __restrict__ offs, float* __restrict__ avglog){
    __shared__ int sd[1024];
    __shared__ float sf[1024];
    __shared__ int carry;
    if (threadIdx.x == 0) carry = 0;
    __syncthreads();
    float ls = 0.f;
    for (int base = 0; base < N_; base += 1024){
        int i = base + threadIdx.x;
        int v = (i < N_) ? deg_i[i] : 0;
        if (i < N_) ls += logf((float)v + 1.f);
        sd[threadIdx.x] = v;
        __syncthreads();
        for (int off = 1; off < 1024; off <<= 1){
            int t = (threadIdx.x >= off) ? sd[threadIdx.x - off] : 0;
            __syncthreads();
            sd[threadIdx.x] += t;
            __syncthreads();
        }
        if (i < N_) offs[i] = carry + sd[threadIdx.x] - v;
        __syncthreads();
        if (threadIdx.x == 0) carry += sd[1023];
        __syncthreads();
    }
    if (threadIdx.x == 0) offs[N_] = carry;
    sf[threadIdx.x] = ls;
    __syncthreads();
    for (int off = 512; off > 0; off >>= 1){
        if (threadIdx.x < off) sf[threadIdx.x] += sf[threadIdx.x + off];
        __syncthreads();
    }
    if (threadIdx.x == 0) avglog[0] = sf[0] / (float)N_;
}

__global__ void k_fill(const int* __restrict__ ei, const int* __restrict__ eattr,
                       const int* __restrict__ offs, int* __restrict__ cursor, int* __restrict__ csr){
    int e = blockIdx.x*blockDim.x + threadIdx.x;
    if (e >= E_) return;
    int d = ei[E_ + e];
    int pos = offs[d] + atomicAdd(&cursor[d], 1);
    csr[pos] = ei[e] | (eattr[e] << 16);
}

__global__ void k_amp(const int* __restrict__ deg_i, const float* __restrict__ avglog,
                      float* __restrict__ ampv, float* __restrict__ iampv){
    int n = blockIdx.x*blockDim.x + threadIdx.x;
    if (n >= N_) return;
    float dm = fmaxf((float)deg_i[n], 1.f);
    float a = logf(dm + 1.f) / avglog[0];
    ampv[n] = a;
    iampv[n] = 1.f / a;
}

__global__ void k_eemb(const float* __restrict__ edge_emb, const float* __restrict__ We,
                       const float* __restrict__ be, float* __restrict__ eembw){
    int i = blockIdx.x*blockDim.x + threadIdx.x;
    if (i >= 4*4*FIN_) return;
    int c = i % FIN_;
    int a = (i / FIN_) % 4;
    int l = i / (4*FIN_);
    float s = be[l*FIN_ + c];
    for (int k = 0; k < ED_; k++) s = fmaf(edge_emb[a*ED_ + k], We[(l*ED_ + k)*FIN_ + c], s);
    eembw[i] = s;
}

__global__ void k_tbl(const float* __restrict__ eembw, const float* __restrict__ Wpre,
                      const float* __restrict__ bpre, float* __restrict__ tbl){
    int i = blockIdx.x*blockDim.x + threadIdx.x;
    if (i >= 4*4*TF_) return;
    int f = i % FIN_;
    int t = (i / FIN_) % T_;
    int a = (i / TF_) % 4;
    int l = i / (4*TF_);
    float s = bpre[(l*T_ + t)*FIN_ + f];
    const float* em = eembw + (l*4 + a)*FIN_;
    const float* W3 = Wpre + ((size_t)(l*T_ + t)*225 + 2*FIN_)*FIN_;
    for (int c = 0; c < FIN_; c++) s = fmaf(em[c], W3[c*FIN_ + f], s);
    tbl[i] = s;
}

// Wcomb[l,t,c,j]: 375x48 per (l,t). c: 0..74 h, 75..374 agg (kind-major). j: 0..14 y1, 15..29 y2(amp), 30..44 y3(iamp)
__global__ void k_wcomb(const float* __restrict__ Wpost, float* __restrict__ Wcomb){
    int i = blockIdx.x*blockDim.x + threadIdx.x;
    if (i >= 4*T_*TF_*YC_) return;
    int j = i % YC_;
    int c = (i / YC_) % TF_;
    int t = (i / (YC_*TF_)) % T_;
    int l = i / (YC_*TF_*T_);
    float v = 0.f;
    if (j < 45){
        int blk = j / 15, fo = j % 15;
        const float* Wp = Wpost + (size_t)(l*T_ + t)*975*15;
        if (c < FIN_){ if (blk == 0) v = Wp[c*15 + fo]; }
        else { int jj = c - FIN_; v = Wp[(FIN_ + blk*AGGW_ + jj)*15 + fo]; }
    }
    Wcomb[i] = v;
}

// zero-padded Wlin: [l][75][80]
__global__ void k_wlin80(const float* __restrict__ Wlin, float* __restrict__ Wlin80){
    int i = blockIdx.x*blockDim.x + threadIdx.x;
    if (i >= 4*FIN_*80) return;
    int q = i % 80;
    int p = (i / 80) % FIN_;
    int l = i / (80*FIN_);
    Wlin80[i] = (q < FIN_) ? Wlin[(l*FIN_ + p)*FIN_ + q] : 0.f;
}

// ---- per-layer kernels ----
// thread-per-row GEMM, weights via wave-uniform (scalar) loads.
// chunk = t*2+half. half=0 -> Af (f32), half=1 -> Bh (f16)
__global__ void __launch_bounds__(64) k_A(const float* __restrict__ hT, const float* __restrict__ Wpre_l,
                                          float* __restrict__ Af, __half* __restrict__ Bh){
    int chunk = blockIdx.y;
    int t = chunk >> 1, half = chunk & 1;
    const float* __restrict__ W = Wpre_l + (size_t)(t*225 + half*FIN_)*FIN_;
    int n = blockIdx.x*64 + threadIdx.x;
    int nn = (n < N_) ? n : N_-1;
    float acc[80];
    #pragma unroll
    for (int j = 0; j < 80; j++) acc[j] = 0.f;
    #pragma unroll 1
    for (int c4 = 0; c4 < 18; c4++){
        float i0 = hT[(size_t)(c4*4+0)*NP_ + nn];
        float i1 = hT[(size_t)(c4*4+1)*NP_ + nn];
        float i2 = hT[(size_t)(c4*4+2)*NP_ + nn];
        float i3 = hT[(size_t)(c4*4+3)*NP_ + nn];
        const float* W0 = W + c4*4*FIN_;
        #pragma unroll
        for (int j = 0; j < FIN_; j++){
            acc[j] = fmaf(i0, W0[j], acc[j]);
            acc[j] = fmaf(i1, W0[FIN_ + j], acc[j]);
            acc[j] = fmaf(i2, W0[2*FIN_ + j], acc[j]);
            acc[j] = fmaf(i3, W0[3*FIN_ + j], acc[j]);
        }
    }
    {   // tail c = 72..74
        float i0 = hT[(size_t)72*NP_ + nn];
        float i1 = hT[(size_t)73*NP_ + nn];
        float i2 = hT[(size_t)74*NP_ + nn];
        const float* W0 = W + 72*FIN_;
        #pragma unroll
        for (int j = 0; j < FIN_; j++){
            acc[j] = fmaf(i0, W0[j], acc[j]);
            acc[j] = fmaf(i1, W0[FIN_ + j], acc[j]);
            acc[j] = fmaf(i2, W0[2*FIN_ + j], acc[j]);
        }
    }
    if (n < N_){
        if (half == 0){
            float4* o = (float4*)(Af + (size_t)n*AW_ + t*80);
            #pragma unroll
            for (int j4 = 0; j4 < 20; j4++)
                o[j4] = make_float4(acc[4*j4], acc[4*j4+1], acc[4*j4+2], acc[4*j4+3]);
        } else {
            unsigned u[40];
            #pragma unroll
            for (int k = 0; k < 40; k++) u[k] = pack2h(acc[2*k], acc[2*k+1]);
            uint4* o = (uint4*)(Bh + (size_t)n*AW_ + t*80);
            #pragma unroll
            for (int j = 0; j < 10; j++) o[j] = make_uint4(u[4*j], u[4*j+1], u[4*j+2], u[4*j+3]);
        }
    }
}

// per-node CSR aggregation -> packed float4 {mean,mn,mx,sd} at agg2[(t*75+fi)*NP_ + n]
__global__ void __launch_bounds__(128) k_agg(const float* __restrict__ Af, const __half* __restrict__ Bh,
                                             const int* __restrict__ offs, const int* __restrict__ csr,
                                             const float* __restrict__ tbl_l, float4* __restrict__ agg2){
    __shared__ float tl[4*TF_];
    int bid = blockIdx.x;
    int n = (bid & 7)*1250 + (bid >> 3);   // XCD swizzle: line-sharing nodes on one XCD
    for (int idx = threadIdx.x; idx < 4*TF_; idx += 128) tl[idx] = tbl_l[idx];
    __syncthreads();
    int s = offs[n], e_end = offs[n+1];
    int f0 = threadIdx.x;
    int f1 = threadIdx.x + 128;
    int f2r = threadIdx.x + 256;
    int f2 = (f2r < TF_) ? f2r : 0;
    int ao0 = (f0/FIN_)*80 + f0%FIN_;
    int ao1 = (f1/FIN_)*80 + f1%FIN_;
    int ao2 = (f2/FIN_)*80 + f2%FIN_;
    const float* An = Af + (size_t)n*AW_;
    float a0 = An[ao0], a1 = An[ao1], a2 = An[ao2];
    float s0=0.f,s1=0.f,s2=0.f, q0=0.f,q1=0.f,q2=0.f;
    float mn0=INFINITY,mn1=INFINITY,mn2=INFINITY;
    float mx0=-INFINITY,mx1=-INFINITY,mx2=-INFINITY;
    for (int e = s; e < e_end; e++){
        int pk = csr[e];
        int src = pk & 0xFFFF;
        int at = pk >> 16;
        const __half* B = Bh + (size_t)src*AW_;
        const float* tt = tl + at*TF_;
        float m0 = a0 + __half2float(B[ao0]) + tt[f0];
        float m1 = a1 + __half2float(B[ao1]) + tt[f1];
        float m2 = a2 + __half2float(B[ao2]) + tt[f2];
        s0 += m0; s1 += m1; s2 += m2;
        q0 = fmaf(m0,m0,q0); q1 = fmaf(m1,m1,q1); q2 = fmaf(m2,m2,q2);
        mn0 = fminf(mn0,m0); mn1 = fminf(mn1,m1); mn2 = fminf(mn2,m2);
        mx0 = fmaxf(mx0,m0); mx1 = fmaxf(mx1,m1); mx2 = fmaxf(mx2,m2);
    }
    float deg = (float)(e_end - s);
    float dc = fmaxf(deg, 1.f);
    float inv = 1.f / dc;
    bool empty = (deg == 0.f);
    {
        float mean = s0*inv;
        float sd = sqrtf(fmaxf(q0*inv - mean*mean, 0.f) + 1e-5f);
        int t = f0/FIN_, fi = f0%FIN_;
        agg2[(size_t)(t*FIN_+fi)*NP_ + n] = make_float4(mean, empty?0.f:mn0, empty?0.f:mx0, sd);
    }
    {
        float mean = s1*inv;
        float sd = sqrtf(fmaxf(q1*inv - mean*mean, 0.f) + 1e-5f);
        int t = f1/FIN_, fi = f1%FIN_;
        agg2[(size_t)(t*FIN_+fi)*NP_ + n] = make_float4(mean, empty?0.f:mn1, empty?0.f:mx1, sd);
    }
    if (f2r < TF_){
        float mean = s2*inv;
        float sd = sqrtf(fmaxf(q2*inv - mean*mean, 0.f) + 1e-5f);
        int t = f2r/FIN_, fi = f2r%FIN_;
        agg2[(size_t)(t*FIN_+fi)*NP_ + n] = make_float4(mean, empty?0.f:mn2, empty?0.f:mx2, sd);
    }
}

// thread-per-row: YbT[(t*48 + j)*NP_ + n] = [h(75)|agg_t(300)] @ Wcomb[l,t][:, j], all 48 cols
__global__ void __launch_bounds__(64) k_post3(const float* __restrict__ hT, const float4* __restrict__ agg2,
                                              const float* __restrict__ Wcomb_l, float* __restrict__ YbT){
    int t = blockIdx.y;
    const float* __restrict__ W = Wcomb_l + (size_t)t*TF_*YC_;
    int n = blockIdx.x*64 + threadIdx.x;
    int nn = (n < N_) ? n : N_-1;
    float acc[48];
    #pragma unroll
    for (int j = 0; j < 48; j++) acc[j] = 0.f;
    // h part: W rows 0..74
    #pragma unroll 1
    for (int c4 = 0; c4 < 18; c4++){
        float i0 = hT[(size_t)(c4*4+0)*NP_ + nn];
        float i1 = hT[(size_t)(c4*4+1)*NP_ + nn];
        float i2 = hT[(size_t)(c4*4+2)*NP_ + nn];
        float i3 = hT[(size_t)(c4*4+3)*NP_ + nn];
        const float* W0 = W + c4*4*YC_;
        #pragma unroll
        for (int j = 0; j < 48; j++){
            acc[j] = fmaf(i0, W0[j], acc[j]);
            acc[j] = fmaf(i1, W0[YC_ + j], acc[j]);
            acc[j] = fmaf(i2, W0[2*YC_ + j], acc[j]);
            acc[j] = fmaf(i3, W0[3*YC_ + j], acc[j]);
        }
    }
    {
        float i0 = hT[(size_t)72*NP_ + nn];
        float i1 = hT[(size_t)73*NP_ + nn];
        float i2 = hT[(size_t)74*NP_ + nn];
        const float* W0 = W + 72*YC_;
        #pragma unroll
        for (int j = 0; j < 48; j++){
            acc[j] = fmaf(i0, W0[j], acc[j]);
            acc[j] = fmaf(i1, W0[YC_ + j], acc[j]);
            acc[j] = fmaf(i2, W0[2*YC_ + j], acc[j]);
        }
    }
    // agg part: per fi one coalesced b128 {mean,mn,mx,sd}; W rows 75 + kind*75 + fi
    const float4* ap = agg2 + (size_t)t*FIN_*NP_ + nn;
    #pragma unroll 1
    for (int fi = 0; fi < FIN_; fi++){
        float4 m = ap[(size_t)fi*NP_];
        const float* Wm = W + (FIN_ + fi)*YC_;
        #pragma unroll
        for (int j = 0; j < 48; j++){
            acc[j] = fmaf(m.x, Wm[j], acc[j]);
            acc[j] = fmaf(m.y, Wm[FIN_*YC_ + j], acc[j]);
            acc[j] = fmaf(m.z, Wm[2*FIN_*YC_ + j], acc[j]);
            acc[j] = fmaf(m.w, Wm[3*FIN_*YC_ + j], acc[j]);
        }
    }
    if (n < N_){
        #pragma unroll
        for (int j = 0; j < 48; j++) YbT[(size_t)(t*YC_ + j)*NP_ + n] = acc[j];
    }
}

// combine + Wlin + BN stats; thread-per-row; q-range split over blockIdx.y (0: 0..39, 1: 40..74)
__global__ void __launch_bounds__(64) k_Y(const float* __restrict__ YbT, const float* __restrict__ ampv,
                                          const float* __restrict__ iampv, const float* __restrict__ bpost_l,
                                          const float* __restrict__ Wlin80_l, const float* __restrict__ blin_l,
                                          float* __restrict__ olinT, float* __restrict__ bnsum, float* __restrict__ bnsq){
    __shared__ float st[64*77];
    int qbase = blockIdx.y * 40;
    int qcnt  = blockIdx.y ? 35 : 40;
    int n = blockIdx.x*64 + threadIdx.x;
    int nn = (n < N_) ? n : N_-1;
    bool valid = (n < N_);
    float amp = ampv[nn], iamp = iampv[nn];
    #pragma unroll 1
    for (int t = 0; t < T_; t++){
        #pragma unroll
        for (int fo = 0; fo < FOUT_; fo++){
            float v = YbT[(size_t)(t*YC_ + fo)*NP_ + nn]
                    + amp  * YbT[(size_t)(t*YC_ + 15 + fo)*NP_ + nn]
                    + iamp * YbT[(size_t)(t*YC_ + 30 + fo)*NP_ + nn]
                    + bpost_l[t*FOUT_ + fo];
            st[threadIdx.x*77 + t*FOUT_ + fo] = v;
        }
    }
    __syncthreads();
    float acc[40];
    #pragma unroll
    for (int k = 0; k < 40; k++) acc[k] = (qbase + k < FIN_) ? blin_l[qbase + k] : 0.f;
    #pragma unroll 1
    for (int p = 0; p < FIN_; p++){
        float yv = st[threadIdx.x*77 + p];
        const float* Wp = Wlin80_l + p*80 + qbase;   // zero-padded cols -> unguarded
        #pragma unroll
        for (int k = 0; k < 40; k++) acc[k] = fmaf(yv, Wp[k], acc[k]);
    }
    if (valid){
        #pragma unroll
        for (int k = 0; k < 40; k++){
            int q = qbase + k;
            if (q < FIN_) olinT[(size_t)q*NP_ + n] = acc[k];
        }
    }
    __syncthreads();
    #pragma unroll
    for (int k = 0; k < 40; k++) st[threadIdx.x*77 + k] = valid ? acc[k] : 0.f;
    __syncthreads();
    for (int qq = threadIdx.x; qq < qcnt; qq += 64){
        float s = 0.f, s2 = 0.f;
        #pragma unroll 4
        for (int m = 0; m < 64; m++){ float v = st[m*77 + qq]; s += v; s2 = fmaf(v, v, s2); }
        atomicAdd(&bnsum[qbase + qq], s);
        atomicAdd(&bnsq[qbase + qq], s2);
    }
}

__global__ void k_bn(const float* __restrict__ olinT, const float* __restrict__ bnsum, const float* __restrict__ bnsq,
                     const float* __restrict__ gamma_l, const float* __restrict__ beta_l,
                     const float* __restrict__ uafp, float* __restrict__ hT){
    int i = blockIdx.x*blockDim.x + threadIdx.x;
    if (i >= FIN_*N_) return;
    int q = i / N_, n = i % N_;
    float mu = bnsum[q] * (1.f/(float)N_);
    float var = bnsq[q] * (1.f/(float)N_) - mu*mu;
    float xh = (olinT[(size_t)q*NP_ + n] - mu) * rsqrtf(var + 1e-5f) * gamma_l[q] + beta_l[q];
    hT[(size_t)q*NP_ + n] = uaf_f(xh, uafp);
}

// ---- pooling + MLP ----
// segmented pooling over sorted batch: block per group, wave per feature, lanes over nodes
__global__ void __launch_bounds__(256) k_pool2(const float* __restrict__ hT, const int* __restrict__ batch,
                                               float* __restrict__ pooled){
    __shared__ int sb[2];
    int g = blockIdx.x;
    if (threadIdx.x < 2){
        int key = g + threadIdx.x;      // lower_bound(batch, key)
        int lo = 0, hi = N_;
        while (lo < hi){ int mid = (lo + hi) >> 1; if (batch[mid] < key) lo = mid + 1; else hi = mid; }
        sb[threadIdx.x] = lo;
    }
    __syncthreads();
    int s = sb[0], e = sb[1];
    int wave = threadIdx.x >> 6, lane = threadIdx.x & 63;
    for (int q = wave; q < FIN_; q += 4){
        float sum = 0.f;
        for (int n = s + lane; n < e; n += 64) sum += hT[(size_t)q*NP_ + n];
        #pragma unroll
        for (int off = 32; off > 0; off >>= 1) sum += __shfl_down(sum, off);
        if (lane == 0) pooled[g*FIN_ + q] = sum;
    }
}

__global__ void __launch_bounds__(64) k_mlp(const float* __restrict__ pooled,
        const float* __restrict__ mW1, const float* __restrict__ mb1,
        const float* __restrict__ mW2, const float* __restrict__ mb2,
        const float* __restrict__ mW3, const float* __restrict__ mb3,
        const float* __restrict__ uafp, float* __restrict__ outp){
    __shared__ float pr[FIN_];
    __shared__ float z1[50];
    __shared__ float z2[25];
    int g = blockIdx.x;
    for (int c = threadIdx.x; c < FIN_; c += 64) pr[c] = pooled[g*FIN_ + c];
    __syncthreads();
    if (threadIdx.x < 50){
        float s = mb1[threadIdx.x];
        for (int c = 0; c < FIN_; c++) s = fmaf(pr[c], mW1[c*50 + threadIdx.x], s);
        z1[threadIdx.x] = uaf_f(s, uafp);
    }
    __syncthreads();
    if (threadIdx.x < 25){
        float s = mb2[threadIdx.x];
        for (int c = 0; c < 50; c++) s = fmaf(z1[c], mW2[c*25 + threadIdx.x], s);
        z2[threadIdx.x] = uaf_f(s, uafp);
    }
    __syncthreads();
    if (threadIdx.x == 0){
        float s = mb3[0];
        for (int c = 0; c < 25; c++) s = fmaf(z2[c], mW3[c], s);
        outp[g] = s;
    }
}

extern "C" void kernel_launch(void* const* d_in, const int* in_sizes, int n_in,
                              void* d_out, int out_size, void* d_ws, size_t ws_size,
                              hipStream_t stream) {
    const int* x         = (const int*)d_in[0];
    const int* ei        = (const int*)d_in[1];
    const int* eattr     = (const int*)d_in[2];
    const int* batch     = (const int*)d_in[3];
    const float* node_emb= (const float*)d_in[4];
    const float* edge_emb= (const float*)d_in[5];
    const float* We      = (const float*)d_in[6];
    const float* be      = (const float*)d_in[7];
    const float* Wpre    = (const float*)d_in[8];
    const float* bpre    = (const float*)d_in[9];
    const float* Wpost   = (const float*)d_in[10];
    const float* bpost   = (const float*)d_in[11];
    const float* Wlin    = (const float*)d_in[12];
    const float* blin    = (const float*)d_in[13];
    const float* bn_gamma= (const float*)d_in[14];
    const float* bn_beta = (const float*)d_in[15];
    const float* uafp    = (const float*)d_in[16];
    const float* mW1     = (const float*)d_in[17];
    const float* mb1     = (const float*)d_in[18];
    const float* mW2     = (const float*)d_in[19];
    const float* mb2     = (const float*)d_in[20];
    const float* mW3     = (const float*)d_in[21];
    const float* mb3     = (const float*)d_in[22];
    float* outp          = (float*)d_out;

    char* w = (char*)d_ws;
    auto alloc = [&](size_t bytes) -> void* {
        void* p = (void*)w;
        w += (bytes + 255) & ~(size_t)255;
        return p;
    };
    float*  hT    = (float*)alloc((size_t)FIN_*NP_*4);
    float*  Af    = (float*)alloc((size_t)N_*AW_*4);           // 16 MB
    __half* Bh    = (__half*)alloc((size_t)N_*AW_*2);          // 8 MB
    float4* agg2  = (float4*)alloc((size_t)TF_*NP_*16);        // 60.3 MB
    float*  YbT   = Af;                  // alias: Af dead after k_agg (9.65 MB)
    float*  olinT = Af + 3000000;        // alias at +12 MB (3 MB), disjoint from YbT
    float*  ampv  = (float*)alloc(N_*4);
    float*  iampv = (float*)alloc(N_*4);
    float*  avglog= (float*)alloc(4);
    float*  tbl   = (float*)alloc(4*4*TF_*4);
    float*  eembw = (float*)alloc(4*4*FIN_*4);
    float*  Wcomb = (float*)alloc((size_t)4*T_*TF_*YC_*4);
    float*  Wlin80= (float*)alloc(4*FIN_*80*4);
    float*  bnsum = (float*)alloc(2*FIN_*4);
    float*  bnsq  = bnsum + FIN_;
    float*  pooled= (float*)alloc(G_*FIN_*4);
    int* deg_i   = (int*)alloc(N_*4);
    int* offs    = (int*)alloc((N_+1)*4);
    int* cursor  = (int*)alloc(N_*4);
    int* csr     = (int*)alloc(E_*4);

    hipMemsetAsync(deg_i, 0, N_*4, stream);
    hipMemsetAsync(cursor, 0, N_*4, stream);

    k_h0<<<(FIN_*N_ + 255)/256, 256, 0, stream>>>(x, node_emb, hT);
    k_deg<<<(E_ + 255)/256, 256, 0, stream>>>(ei, deg_i);
    k_scan<<<1, 1024, 0, stream>>>(deg_i, offs, avglog);
    k_fill<<<(E_ + 255)/256, 256, 0, stream>>>(ei, eattr, offs, cursor, csr);
    k_amp<<<(N_ + 255)/256, 256, 0, stream>>>(deg_i, avglog, ampv, iampv);
    k_eemb<<<(4*4*FIN_ + 255)/256, 256, 0, stream>>>(edge_emb, We, be, eembw);
    k_tbl<<<(4*4*TF_ + 255)/256, 256, 0, stream>>>(eembw, Wpre, bpre, tbl);
    k_wcomb<<<(4*T_*TF_*YC_ + 255)/256, 256, 0, stream>>>(Wpost, Wcomb);
    k_wlin80<<<(4*FIN_*80 + 255)/256, 256, 0, stream>>>(Wlin, Wlin80);

    int nrb = (N_ + 63)/64;  // 157
    for (int l = 0; l < 4; l++){
        hipMemsetAsync(bnsum, 0, 2*FIN_*4, stream);
        k_A<<<dim3(nrb, 10), 64, 0, stream>>>(hT, Wpre + (size_t)l*T_*225*FIN_, Af, Bh);
        k_agg<<<N_, 128, 0, stream>>>(Af, Bh, offs, csr, tbl + (size_t)l*4*TF_, agg2);
        k_post3<<<dim3(nrb, T_), 64, 0, stream>>>(hT, agg2, Wcomb + (size_t)l*T_*TF_*YC_, YbT);
        k_Y<<<dim3(nrb, 2), 64, 0, stream>>>(YbT, ampv, iampv, bpost + l*T_*FOUT_,
                                             Wlin80 + (size_t)l*FIN_*80, blin + l*FIN_,
                                             olinT, bnsum, bnsq);
        k_bn<<<(FIN_*N_ + 255)/256, 256, 0, stream>>>(olinT, bnsum, bnsq,
                                                      bn_gamma + l*FIN_, bn_beta + l*FIN_, uafp, hT);
    }

    k_pool2<<<G_, 256, 0, stream>>>(hT, batch, pooled);
    k_mlp<<<G_, 64, 0, stream>>>(pooled, mW1, mb1, mW2, mb2, mW3, mb3, uafp, outp);
}

// Round 7
// 1016.581 us; speedup vs baseline: 1.1839x; 1.1804x over previous
//
#include <hip/hip_runtime.h>
#include <hip/hip_fp16.h>
#include <math.h>

// ---- problem constants ----
static constexpr int N_   = 10000;
static constexpr int E_   = 160000;
static constexpr int G_   = 64;
static constexpr int T_   = 5;
static constexpr int FIN_ = 75;
static constexpr int ED_  = 50;
static constexpr int FOUT_= 15;
static constexpr int TF_  = T_*FIN_;     // 375
static constexpr int AGGW_= 4*FIN_;      // 300
static constexpr int YC_  = 48;          // padded 45 -> 48 combined outputs
static constexpr int NP_  = 10048;       // padded node count (column-major feature rows)
static constexpr int AW_  = 400;         // Af/Bh row: 5 chunks x 80

// ---- UAF ----
__device__ __forceinline__ float softplus_f(float x){
    return fmaxf(x, 0.f) + log1pf(expf(-fabsf(x)));
}
__device__ __forceinline__ float uaf_f(float v, const float* __restrict__ p){
    return softplus_f(p[0]*(v + p[1]) + p[2]*v*v) - softplus_f(p[3]*(v - p[1])) + p[4];
}
__device__ __forceinline__ unsigned pack2h(float a, float b){
    __half2 h = __floats2half2_rn(a, b);
    return *reinterpret_cast<unsigned*>(&h);
}

// ---- setup kernels ----
__global__ void k_h0(const int* __restrict__ x, const float* __restrict__ node_emb, float* __restrict__ hT){
    int i = blockIdx.x*blockDim.x + threadIdx.x;
    if (i >= FIN_*N_) return;
    int q = i / N_, n = i % N_;
    hT[(size_t)q*NP_ + n] = node_emb[x[n]*FIN_ + q];
}

__global__ void k_deg(const int* __restrict__ ei, int* __restrict__ deg_i){
    int e = blockIdx.x*blockDim.x + threadIdx.x;
    if (e >= E_) return;
    atomicAdd(&deg_i[ei[E_ + e]], 1);
}

__global__ void k_scan(const int* __restrict__ deg_i, int* __restrict__ offs, float* __restrict__ avglog){
    __shared__ int sd[1024];
    __shared__ float sf[1024];
    __shared__ int carry;
    if (threadIdx.x == 0) carry = 0;
    __syncthreads();
    float ls = 0.f;
    for (int base = 0; base < N_; base += 1024){
        int i = base + threadIdx.x;
        int v = (i < N_) ? deg_i[i] : 0;
        if (i < N_) ls += logf((float)v + 1.f);
        sd[threadIdx.x] = v;
        __syncthreads();
        for (int off = 1; off < 1024; off <<= 1){
            int t = (threadIdx.x >= off) ? sd[threadIdx.x - off] : 0;
            __syncthreads();
            sd[threadIdx.x] += t;
            __syncthreads();
        }
        if (i < N_) offs[i] = carry + sd[threadIdx.x] - v;
        __syncthreads();
        if (threadIdx.x == 0) carry += sd[1023];
        __syncthreads();
    }
    if (threadIdx.x == 0) offs[N_] = carry;
    sf[threadIdx.x] = ls;
    __syncthreads();
    for (int off = 512; off > 0; off >>= 1){
        if (threadIdx.x < off) sf[threadIdx.x] += sf[threadIdx.x + off];
        __syncthreads();
    }
    if (threadIdx.x == 0) avglog[0] = sf[0] / (float)N_;
}

__global__ void k_fill(const int* __restrict__ ei, const int* __restrict__ eattr,
                       const int* __restrict__ offs, int* __restrict__ cursor, int* __restrict__ csr){
    int e = blockIdx.x*blockDim.x + threadIdx.x;
    if (e >= E_) return;
    int d = ei[E_ + e];
    int pos = offs[d] + atomicAdd(&cursor[d], 1);
    csr[pos] = ei[e] | (eattr[e] << 16);
}

__global__ void k_amp(const int* __restrict__ deg_i, const float* __restrict__ avglog,
                      float* __restrict__ ampv, float* __restrict__ iampv){
    int n = blockIdx.x*blockDim.x + threadIdx.x;
    if (n >= N_) return;
    float dm = fmaxf((float)deg_i[n], 1.f);
    float a = logf(dm + 1.f) / avglog[0];
    ampv[n] = a;
    iampv[n] = 1.f / a;
}

__global__ void k_eemb(const float* __restrict__ edge_emb, const float* __restrict__ We,
                       const float* __restrict__ be, float* __restrict__ eembw){
    int i = blockIdx.x*blockDim.x + threadIdx.x;
    if (i >= 4*4*FIN_) return;
    int c = i % FIN_;
    int a = (i / FIN_) % 4;
    int l = i / (4*FIN_);
    float s = be[l*FIN_ + c];
    for (int k = 0; k < ED_; k++) s = fmaf(edge_emb[a*ED_ + k], We[(l*ED_ + k)*FIN_ + c], s);
    eembw[i] = s;
}

__global__ void k_tbl(const float* __restrict__ eembw, const float* __restrict__ Wpre,
                      const float* __restrict__ bpre, float* __restrict__ tbl){
    int i = blockIdx.x*blockDim.x + threadIdx.x;
    if (i >= 4*4*TF_) return;
    int f = i % FIN_;
    int t = (i / FIN_) % T_;
    int a = (i / TF_) % 4;
    int l = i / (4*TF_);
    float s = bpre[(l*T_ + t)*FIN_ + f];
    const float* em = eembw + (l*4 + a)*FIN_;
    const float* W3 = Wpre + ((size_t)(l*T_ + t)*225 + 2*FIN_)*FIN_;
    for (int c = 0; c < FIN_; c++) s = fmaf(em[c], W3[c*FIN_ + f], s);
    tbl[i] = s;
}

// Wcomb[l,t,c2,j]: 375x48 per (l,t). K-order c2: 0..74 h; 75+: kind-INTERLEAVED per fi
// (c2 = 75 + fi*4 + kind, kind in {mean,mn,mx,sd}) so one agg2 float4 = 4 consecutive K-rows.
// j: 0..14 y1, 15..29 y2(amp), 30..44 y3(iamp), 45..47 zero
__global__ void k_wcomb(const float* __restrict__ Wpost, float* __restrict__ Wcomb){
    int i = blockIdx.x*blockDim.x + threadIdx.x;
    if (i >= 4*T_*TF_*YC_) return;
    int j = i % YC_;
    int c = (i / YC_) % TF_;
    int t = (i / (YC_*TF_)) % T_;
    int l = i / (YC_*TF_*T_);
    float v = 0.f;
    if (j < 45){
        int blk = j / 15, fo = j % 15;
        const float* Wp = Wpost + (size_t)(l*T_ + t)*975*15;
        if (c < FIN_){ if (blk == 0) v = Wp[c*15 + fo]; }
        else {
            int r = c - FIN_;
            int fi = r >> 2, kind = r & 3;
            int jj = kind*FIN_ + fi;
            v = Wp[(FIN_ + blk*AGGW_ + jj)*15 + fo];
        }
    }
    Wcomb[i] = v;
}

// zero-padded Wlin: [l][75][80]
__global__ void k_wlin80(const float* __restrict__ Wlin, float* __restrict__ Wlin80){
    int i = blockIdx.x*blockDim.x + threadIdx.x;
    if (i >= 4*FIN_*80) return;
    int q = i % 80;
    int p = (i / 80) % FIN_;
    int l = i / (80*FIN_);
    Wlin80[i] = (q < FIN_) ? Wlin[(l*FIN_ + p)*FIN_ + q] : 0.f;
}

// ---- per-layer kernels ----
// 2D micro-tiled GEMM: M-tile 128 nodes, N-tile 80 (one chunk), K=75 fully staged.
// chunk = blockIdx.y = t*2+half. half=0 -> Af (f32), half=1 -> Bh (f16).
// 256 threads: tn=tid&31 (4 nodes each), tj=tid>>5 (10 cols each). acc[4][10].
__global__ void __launch_bounds__(256) k_A2(const float* __restrict__ hT, const float* __restrict__ Wpre_l,
                                            float* __restrict__ Af, __half* __restrict__ Bh){
    __shared__ float Act[FIN_*128];   // 38.4 KB
    __shared__ float Wt[FIN_*80];     // 24 KB
    int chunk = blockIdx.y;
    int t = chunk >> 1, half = chunk & 1;
    const float* __restrict__ W = Wpre_l + (size_t)(t*225 + half*FIN_)*FIN_;
    int n0 = blockIdx.x * 128;
    int tid = threadIdx.x;
    for (int i = tid; i < FIN_*80; i += 256){
        int r = i / 80, c = i - r*80;
        Wt[i] = (c < FIN_) ? W[r*FIN_ + c] : 0.f;
    }
    for (int i = tid; i < FIN_*128; i += 256){
        int r = i >> 7, n = i & 127;
        Act[i] = hT[(size_t)r*NP_ + n0 + n];
    }
    __syncthreads();
    int tn = tid & 31, tj = tid >> 5;
    float acc[4][10];
    #pragma unroll
    for (int m = 0; m < 4; m++)
        #pragma unroll
        for (int j = 0; j < 10; j++) acc[m][j] = 0.f;
    #pragma unroll 5
    for (int k = 0; k < FIN_; k++){
        float4 av = *(const float4*)(Act + (k<<7) + (tn<<2));
        const float* wr = Wt + k*80 + tj*10;
        #pragma unroll
        for (int j = 0; j < 10; j++){
            float wv = wr[j];
            acc[0][j] = fmaf(av.x, wv, acc[0][j]);
            acc[1][j] = fmaf(av.y, wv, acc[1][j]);
            acc[2][j] = fmaf(av.z, wv, acc[2][j]);
            acc[3][j] = fmaf(av.w, wv, acc[3][j]);
        }
    }
    int nodeb = n0 + tn*4;
    #pragma unroll
    for (int m = 0; m < 4; m++){
        int node = nodeb + m;
        if (node >= N_) continue;
        if (half == 0){
            float2* dst = (float2*)(Af + (size_t)node*AW_ + t*80 + tj*10);
            #pragma unroll
            for (int j = 0; j < 5; j++) dst[j] = make_float2(acc[m][2*j], acc[m][2*j+1]);
        } else {
            unsigned* dst = (unsigned*)(Bh + (size_t)node*AW_ + t*80 + tj*10);
            #pragma unroll
            for (int j = 0; j < 5; j++) dst[j] = pack2h(acc[m][2*j], acc[m][2*j+1]);
        }
    }
}

// per-node CSR aggregation -> packed float4 {mean,mn,mx,sd} at agg2[(t*75+fi)*NP_ + n]
__global__ void __launch_bounds__(128) k_agg(const float* __restrict__ Af, const __half* __restrict__ Bh,
                                             const int* __restrict__ offs, const int* __restrict__ csr,
                                             const float* __restrict__ tbl_l, float4* __restrict__ agg2){
    __shared__ float tl[4*TF_];
    int bid = blockIdx.x;
    int n = (bid & 7)*1250 + (bid >> 3);   // XCD swizzle: line-sharing nodes on one XCD
    for (int idx = threadIdx.x; idx < 4*TF_; idx += 128) tl[idx] = tbl_l[idx];
    __syncthreads();
    int s = offs[n], e_end = offs[n+1];
    int f0 = threadIdx.x;
    int f1 = threadIdx.x + 128;
    int f2r = threadIdx.x + 256;
    int f2 = (f2r < TF_) ? f2r : 0;
    int ao0 = (f0/FIN_)*80 + f0%FIN_;
    int ao1 = (f1/FIN_)*80 + f1%FIN_;
    int ao2 = (f2/FIN_)*80 + f2%FIN_;
    const float* An = Af + (size_t)n*AW_;
    float a0 = An[ao0], a1 = An[ao1], a2 = An[ao2];
    float s0=0.f,s1=0.f,s2=0.f, q0=0.f,q1=0.f,q2=0.f;
    float mn0=INFINITY,mn1=INFINITY,mn2=INFINITY;
    float mx0=-INFINITY,mx1=-INFINITY,mx2=-INFINITY;
    for (int e = s; e < e_end; e++){
        int pk = csr[e];
        int src = pk & 0xFFFF;
        int at = pk >> 16;
        const __half* B = Bh + (size_t)src*AW_;
        const float* tt = tl + at*TF_;
        float m0 = a0 + __half2float(B[ao0]) + tt[f0];
        float m1 = a1 + __half2float(B[ao1]) + tt[f1];
        float m2 = a2 + __half2float(B[ao2]) + tt[f2];
        s0 += m0; s1 += m1; s2 += m2;
        q0 = fmaf(m0,m0,q0); q1 = fmaf(m1,m1,q1); q2 = fmaf(m2,m2,q2);
        mn0 = fminf(mn0,m0); mn1 = fminf(mn1,m1); mn2 = fminf(mn2,m2);
        mx0 = fmaxf(mx0,m0); mx1 = fmaxf(mx1,m1); mx2 = fmaxf(mx2,m2);
    }
    float deg = (float)(e_end - s);
    float dc = fmaxf(deg, 1.f);
    float inv = 1.f / dc;
    bool empty = (deg == 0.f);
    {
        float mean = s0*inv;
        float sd = sqrtf(fmaxf(q0*inv - mean*mean, 0.f) + 1e-5f);
        int t = f0/FIN_, fi = f0%FIN_;
        agg2[(size_t)(t*FIN_+fi)*NP_ + n] = make_float4(mean, empty?0.f:mn0, empty?0.f:mx0, sd);
    }
    {
        float mean = s1*inv;
        float sd = sqrtf(fmaxf(q1*inv - mean*mean, 0.f) + 1e-5f);
        int t = f1/FIN_, fi = f1%FIN_;
        agg2[(size_t)(t*FIN_+fi)*NP_ + n] = make_float4(mean, empty?0.f:mn1, empty?0.f:mx1, sd);
    }
    if (f2r < TF_){
        float mean = s2*inv;
        float sd = sqrtf(fmaxf(q2*inv - mean*mean, 0.f) + 1e-5f);
        int t = f2r/FIN_, fi = f2r%FIN_;
        agg2[(size_t)(t*FIN_+fi)*NP_ + n] = make_float4(mean, empty?0.f:mn2, empty?0.f:mx2, sd);
    }
}

// 2D micro-tiled GEMM: YbT[(t*48+col)*NP + n] = [h(75)|agg_t(300 interleaved)] @ Wcomb[l,t]
// M-tile 128, N=48, K=375. 256 threads: tn=tid&31 (4 nodes), tj=tid>>5 (6 cols). acc[4][6].
__global__ void __launch_bounds__(256) k_post4(const float* __restrict__ hT, const float4* __restrict__ agg2,
                                               const float* __restrict__ Wcomb_l, float* __restrict__ YbT){
    __shared__ float Act[25*128];    // 12.8 KB
    __shared__ float Wt[25*YC_];     // 4.8 KB
    int t = blockIdx.y;
    int n0 = blockIdx.x * 128;
    int tid = threadIdx.x;
    int tn = tid & 31, tj = tid >> 5;
    const float* __restrict__ W = Wcomb_l + (size_t)t*TF_*YC_;
    float acc[4][6];
    #pragma unroll
    for (int m = 0; m < 4; m++)
        #pragma unroll
        for (int j = 0; j < 6; j++) acc[m][j] = 0.f;

    // Phase A: h rows 0..74, 3 chunks of 25
    for (int ch = 0; ch < 3; ch++){
        __syncthreads();
        for (int i = tid; i < 25*YC_; i += 256) Wt[i] = W[ch*25*YC_ + i];
        for (int i = tid; i < 25*128; i += 256){
            int r = i >> 7, n = i & 127;
            Act[i] = hT[(size_t)(ch*25 + r)*NP_ + n0 + n];
        }
        __syncthreads();
        #pragma unroll
        for (int k = 0; k < 25; k++){
            float4 av = *(const float4*)(Act + (k<<7) + (tn<<2));
            const float* wr = Wt + k*YC_ + tj*6;
            #pragma unroll
            for (int j = 0; j < 6; j++){
                float wv = wr[j];
                acc[0][j] = fmaf(av.x, wv, acc[0][j]);
                acc[1][j] = fmaf(av.y, wv, acc[1][j]);
                acc[2][j] = fmaf(av.z, wv, acc[2][j]);
                acc[3][j] = fmaf(av.w, wv, acc[3][j]);
            }
        }
    }
    // Phase B: agg rows (kind-interleaved), 15 chunks of 20 (5 fi-quads)
    const float4* ag = agg2 + (size_t)t*FIN_*NP_;
    for (int ch = 0; ch < 15; ch++){
        __syncthreads();
        for (int i = tid; i < 20*YC_; i += 256) Wt[i] = W[(FIN_ + ch*20)*YC_ + i];
        for (int i = tid; i < 5*128; i += 256){
            int fq = i >> 7, n = i & 127;
            float4 v = ag[(size_t)(ch*5 + fq)*NP_ + n0 + n];
            Act[(fq*4+0)*128 + n] = v.x;
            Act[(fq*4+1)*128 + n] = v.y;
            Act[(fq*4+2)*128 + n] = v.z;
            Act[(fq*4+3)*128 + n] = v.w;
        }
        __syncthreads();
        #pragma unroll
        for (int k = 0; k < 20; k++){
            float4 av = *(const float4*)(Act + (k<<7) + (tn<<2));
            const float* wr = Wt + k*YC_ + tj*6;
            #pragma unroll
            for (int j = 0; j < 6; j++){
                float wv = wr[j];
                acc[0][j] = fmaf(av.x, wv, acc[0][j]);
                acc[1][j] = fmaf(av.y, wv, acc[1][j]);
                acc[2][j] = fmaf(av.z, wv, acc[2][j]);
                acc[3][j] = fmaf(av.w, wv, acc[3][j]);
            }
        }
    }
    // store: coalesced float4 per column
    int nodeb = n0 + tn*4;
    #pragma unroll
    for (int j = 0; j < 6; j++){
        int col = t*YC_ + tj*6 + j;
        float4 v = make_float4(acc[0][j], acc[1][j], acc[2][j], acc[3][j]);
        if (nodeb + 3 < N_){
            *(float4*)(YbT + (size_t)col*NP_ + nodeb) = v;
        } else {
            #pragma unroll
            for (int m = 0; m < 4; m++)
                if (nodeb + m < N_) YbT[(size_t)col*NP_ + nodeb + m] = (&v.x)[m];
        }
    }
}

// combine + Wlin + BN stats; thread-per-row; q-range split over blockIdx.y (0: 0..39, 1: 40..74)
__global__ void __launch_bounds__(64) k_Y(const float* __restrict__ YbT, const float* __restrict__ ampv,
                                          const float* __restrict__ iampv, const float* __restrict__ bpost_l,
                                          const float* __restrict__ Wlin80_l, const float* __restrict__ blin_l,
                                          float* __restrict__ olinT, float* __restrict__ bnsum, float* __restrict__ bnsq){
    __shared__ float st[64*77];
    int qbase = blockIdx.y * 40;
    int qcnt  = blockIdx.y ? 35 : 40;
    int n = blockIdx.x*64 + threadIdx.x;
    int nn = (n < N_) ? n : N_-1;
    bool valid = (n < N_);
    float amp = ampv[nn], iamp = iampv[nn];
    #pragma unroll 1
    for (int t = 0; t < T_; t++){
        #pragma unroll
        for (int fo = 0; fo < FOUT_; fo++){
            float v = YbT[(size_t)(t*YC_ + fo)*NP_ + nn]
                    + amp  * YbT[(size_t)(t*YC_ + 15 + fo)*NP_ + nn]
                    + iamp * YbT[(size_t)(t*YC_ + 30 + fo)*NP_ + nn]
                    + bpost_l[t*FOUT_ + fo];
            st[threadIdx.x*77 + t*FOUT_ + fo] = v;
        }
    }
    __syncthreads();
    float acc[40];
    #pragma unroll
    for (int k = 0; k < 40; k++) acc[k] = (qbase + k < FIN_) ? blin_l[qbase + k] : 0.f;
    #pragma unroll 1
    for (int p = 0; p < FIN_; p++){
        float yv = st[threadIdx.x*77 + p];
        const float* Wp = Wlin80_l + p*80 + qbase;   // zero-padded cols -> unguarded
        #pragma unroll
        for (int k = 0; k < 40; k++) acc[k] = fmaf(yv, Wp[k], acc[k]);
    }
    if (valid){
        #pragma unroll
        for (int k = 0; k < 40; k++){
            int q = qbase + k;
            if (q < FIN_) olinT[(size_t)q*NP_ + n] = acc[k];
        }
    }
    __syncthreads();
    #pragma unroll
    for (int k = 0; k < 40; k++) st[threadIdx.x*77 + k] = valid ? acc[k] : 0.f;
    __syncthreads();
    for (int qq = threadIdx.x; qq < qcnt; qq += 64){
        float s = 0.f, s2 = 0.f;
        #pragma unroll 4
        for (int m = 0; m < 64; m++){ float v = st[m*77 + qq]; s += v; s2 = fmaf(v, v, s2); }
        atomicAdd(&bnsum[qbase + qq], s);
        atomicAdd(&bnsq[qbase + qq], s2);
    }
}

__global__ void k_bn(const float* __restrict__ olinT, const float* __restrict__ bnsum, const float* __restrict__ bnsq,
                     const float* __restrict__ gamma_l, const float* __restrict__ beta_l,
                     const float* __restrict__ uafp, float* __restrict__ hT){
    int i = blockIdx.x*blockDim.x + threadIdx.x;
    if (i >= FIN_*N_) return;
    int q = i / N_, n = i % N_;
    float mu = bnsum[q] * (1.f/(float)N_);
    float var = bnsq[q] * (1.f/(float)N_) - mu*mu;
    float xh = (olinT[(size_t)q*NP_ + n] - mu) * rsqrtf(var + 1e-5f) * gamma_l[q] + beta_l[q];
    hT[(size_t)q*NP_ + n] = uaf_f(xh, uafp);
}

// ---- pooling + MLP ----
// segmented pooling over sorted batch: block per group, wave per feature, lanes over nodes
__global__ void __launch_bounds__(256) k_pool2(const float* __restrict__ hT, const int* __restrict__ batch,
                                               float* __restrict__ pooled){
    __shared__ int sb[2];
    int g = blockIdx.x;
    if (threadIdx.x < 2){
        int key = g + threadIdx.x;      // lower_bound(batch, key)
        int lo = 0, hi = N_;
        while (lo < hi){ int mid = (lo + hi) >> 1; if (batch[mid] < key) lo = mid + 1; else hi = mid; }
        sb[threadIdx.x] = lo;
    }
    __syncthreads();
    int s = sb[0], e = sb[1];
    int wave = threadIdx.x >> 6, lane = threadIdx.x & 63;
    for (int q = wave; q < FIN_; q += 4){
        float sum = 0.f;
        for (int n = s + lane; n < e; n += 64) sum += hT[(size_t)q*NP_ + n];
        #pragma unroll
        for (int off = 32; off > 0; off >>= 1) sum += __shfl_down(sum, off);
        if (lane == 0) pooled[g*FIN_ + q] = sum;
    }
}

__global__ void __launch_bounds__(64) k_mlp(const float* __restrict__ pooled,
        const float* __restrict__ mW1, const float* __restrict__ mb1,
        const float* __restrict__ mW2, const float* __restrict__ mb2,
        const float* __restrict__ mW3, const float* __restrict__ mb3,
        const float* __restrict__ uafp, float* __restrict__ outp){
    __shared__ float pr[FIN_];
    __shared__ float z1[50];
    __shared__ float z2[25];
    int g = blockIdx.x;
    for (int c = threadIdx.x; c < FIN_; c += 64) pr[c] = pooled[g*FIN_ + c];
    __syncthreads();
    if (threadIdx.x < 50){
        float s = mb1[threadIdx.x];
        for (int c = 0; c < FIN_; c++) s = fmaf(pr[c], mW1[c*50 + threadIdx.x], s);
        z1[threadIdx.x] = uaf_f(s, uafp);
    }
    __syncthreads();
    if (threadIdx.x < 25){
        float s = mb2[threadIdx.x];
        for (int c = 0; c < 50; c++) s = fmaf(z1[c], mW2[c*25 + threadIdx.x], s);
        z2[threadIdx.x] = uaf_f(s, uafp);
    }
    __syncthreads();
    if (threadIdx.x == 0){
        float s = mb3[0];
        for (int c = 0; c < 25; c++) s = fmaf(z2[c], mW3[c], s);
        outp[g] = s;
    }
}

extern "C" void kernel_launch(void* const* d_in, const int* in_sizes, int n_in,
                              void* d_out, int out_size, void* d_ws, size_t ws_size,
                              hipStream_t stream) {
    const int* x         = (const int*)d_in[0];
    const int* ei        = (const int*)d_in[1];
    const int* eattr     = (const int*)d_in[2];
    const int* batch     = (const int*)d_in[3];
    const float* node_emb= (const float*)d_in[4];
    const float* edge_emb= (const float*)d_in[5];
    const float* We      = (const float*)d_in[6];
    const float* be      = (const float*)d_in[7];
    const float* Wpre    = (const float*)d_in[8];
    const float* bpre    = (const float*)d_in[9];
    const float* Wpost   = (const float*)d_in[10];
    const float* bpost   = (const float*)d_in[11];
    const float* Wlin    = (const float*)d_in[12];
    const float* blin    = (const float*)d_in[13];
    const float* bn_gamma= (const float*)d_in[14];
    const float* bn_beta = (const float*)d_in[15];
    const float* uafp    = (const float*)d_in[16];
    const float* mW1     = (const float*)d_in[17];
    const float* mb1     = (const float*)d_in[18];
    const float* mW2     = (const float*)d_in[19];
    const float* mb2     = (const float*)d_in[20];
    const float* mW3     = (const float*)d_in[21];
    const float* mb3     = (const float*)d_in[22];
    float* outp          = (float*)d_out;

    char* w = (char*)d_ws;
    auto alloc = [&](size_t bytes) -> void* {
        void* p = (void*)w;
        w += (bytes + 255) & ~(size_t)255;
        return p;
    };
    float*  hT    = (float*)alloc((size_t)FIN_*NP_*4);
    float*  Af    = (float*)alloc((size_t)N_*AW_*4);           // 16 MB
    __half* Bh    = (__half*)alloc((size_t)N_*AW_*2);          // 8 MB
    float4* agg2  = (float4*)alloc((size_t)TF_*NP_*16);        // 60.3 MB
    float*  YbT   = Af;                  // alias: Af dead after k_agg (9.65 MB)
    float*  olinT = Af + 3000000;        // alias at +12 MB (3 MB), disjoint from YbT
    float*  ampv  = (float*)alloc(N_*4);
    float*  iampv = (float*)alloc(N_*4);
    float*  avglog= (float*)alloc(4);
    float*  tbl   = (float*)alloc(4*4*TF_*4);
    float*  eembw = (float*)alloc(4*4*FIN_*4);
    float*  Wcomb = (float*)alloc((size_t)4*T_*TF_*YC_*4);
    float*  Wlin80= (float*)alloc(4*FIN_*80*4);
    float*  bnsum = (float*)alloc(2*FIN_*4);
    float*  bnsq  = bnsum + FIN_;
    float*  pooled= (float*)alloc(G_*FIN_*4);
    int* deg_i   = (int*)alloc(N_*4);
    int* offs    = (int*)alloc((N_+1)*4);
    int* cursor  = (int*)alloc(N_*4);
    int* csr     = (int*)alloc(E_*4);

    hipMemsetAsync(deg_i, 0, N_*4, stream);
    hipMemsetAsync(cursor, 0, N_*4, stream);

    k_h0<<<(FIN_*N_ + 255)/256, 256, 0, stream>>>(x, node_emb, hT);
    k_deg<<<(E_ + 255)/256, 256, 0, stream>>>(ei, deg_i);
    k_scan<<<1, 1024, 0, stream>>>(deg_i, offs, avglog);
    k_fill<<<(E_ + 255)/256, 256, 0, stream>>>(ei, eattr, offs, cursor, csr);
    k_amp<<<(N_ + 255)/256, 256, 0, stream>>>(deg_i, avglog, ampv, iampv);
    k_eemb<<<(4*4*FIN_ + 255)/256, 256, 0, stream>>>(edge_emb, We, be, eembw);
    k_tbl<<<(4*4*TF_ + 255)/256, 256, 0, stream>>>(eembw, Wpre, bpre, tbl);
    k_wcomb<<<(4*T_*TF_*YC_ + 255)/256, 256, 0, stream>>>(Wpost, Wcomb);
    k_wlin80<<<(4*FIN_*80 + 255)/256, 256, 0, stream>>>(Wlin, Wlin80);

    int nmb = (N_ + 127)/128;  // 79 M-tiles
    int nrb = (N_ + 63)/64;    // 157 row-blocks (k_Y)
    for (int l = 0; l < 4; l++){
        hipMemsetAsync(bnsum, 0, 2*FIN_*4, stream);
        k_A2<<<dim3(nmb, 10), 256, 0, stream>>>(hT, Wpre + (size_t)l*T_*225*FIN_, Af, Bh);
        k_agg<<<N_, 128, 0, stream>>>(Af, Bh, offs, csr, tbl + (size_t)l*4*TF_, agg2);
        k_post4<<<dim3(nmb, T_), 256, 0, stream>>>(hT, agg2, Wcomb + (size_t)l*T_*TF_*YC_, YbT);
        k_Y<<<dim3(nrb, 2), 64, 0, stream>>>(YbT, ampv, iampv, bpost + l*T_*FOUT_,
                                             Wlin80 + (size_t)l*FIN_*80, blin + l*FIN_,
                                             olinT, bnsum, bnsq);
        k_bn<<<(FIN_*N_ + 255)/256, 256, 0, stream>>>(olinT, bnsum, bnsq,
                                                      bn_gamma + l*FIN_, bn_beta + l*FIN_, uafp, hT);
    }

    k_pool2<<<G_, 256, 0, stream>>>(hT, batch, pooled);
    k_mlp<<<G_, 64, 0, stream>>>(pooled, mW1, mb1, mW2, mb2, mW3, mb3, uafp, outp);
}